// Round 5
// baseline (5621.184 us; speedup 1.0000x reference)
//
#include <hip/hip_runtime.h>

typedef __attribute__((ext_vector_type(8))) short short8;
typedef __attribute__((ext_vector_type(4))) float f32x4;

#define D_DIM 1024
#define BS 64
#define TSTEPS 512

// ---------------------------------------------------------------------------
// R5: persistent recurrence with 8-wave workgroups (512 thr).
//   - Group bg (16 batches) = 8 WGs x 8 waves (was 64 x 1-wave WGs).
//     Intra-WG sync = HW s_barrier; inter-WG arrivals per step: 8 (was 64).
//   - One counter line per group; wave 0 polls, waves 1-7 wait at s_barrier.
//   - Slab (64 KB) staged cooperatively ONCE per WG; two halves with counted
//     vmcnt so half-B fill overlaps half-A's 48 MFMAs. Raw s_barrier + manual
//     waitcnts (NOT __syncthreads, which would drain vmcnt(0)).
//   - Per-wave math identical to R4 -> bit-identical numerics.
// ---------------------------------------------------------------------------

// state planes: [plane][bg(4)][kc(32)][lane(64)][8 bf16] hi / lo.
// Declared as ull (4 shorts each) so 8B agent atomic stores are well-typed.
__device__ __align__(16) unsigned long long g_s_hi[2][16384];  // 2 x 128 KB
__device__ __align__(16) unsigned long long g_s_lo[2][16384];
// per-group barrier counters: g_cnt[bg*32], one 128B line per group
__device__ unsigned g_cnt[4 * 8 * 32];

__device__ __forceinline__ unsigned short f2bf(float f){
    union { float f; unsigned u; } v; v.f = f;
    unsigned r = v.u + 0x7FFFu + ((v.u >> 16) & 1u);   // RNE
    return (unsigned short)(r >> 16);
}
__device__ __forceinline__ float bf2f(unsigned short h){
    union { unsigned u; float f; } v; v.u = ((unsigned)h) << 16;
    return v.f;
}
__device__ __forceinline__ void split1(float f, unsigned short& h, unsigned short& l){
    h = f2bf(f);
    l = f2bf(f - bf2f(h));
}
__device__ __forceinline__ void split8(const float* __restrict__ p, short8& h8, short8& l8){
    float4 f0 = *(const float4*)p;
    float4 f1 = *(const float4*)(p + 4);
    float v[8] = {f0.x, f0.y, f0.z, f0.w, f1.x, f1.y, f1.z, f1.w};
#pragma unroll
    for (int i = 0; i < 8; ++i){
        unsigned short h, l; split1(v[i], h, l);
        h8[i] = (short)h; l8[i] = (short)l;
    }
}

// async 16B global->LDS (per-lane src, linear wave dest = base + lane*16)
__device__ __forceinline__ void gl_lds16(const unsigned short* g, unsigned short* l){
    __builtin_amdgcn_global_load_lds(
        (__attribute__((address_space(1))) void*)(unsigned long long)(g),
        (__attribute__((address_space(3))) void*)(unsigned int)(unsigned long long)(l),
        16, 0, 0);
}

// ---------------- ext[r][o] = sum_j x[r][j]*Win[o][j], fp32, r = b*512+t.
// Unchanged numerics; also resets the barrier-counter lines each replay.
__global__ __launch_bounds__(256) void ext_gemm(
    const float* __restrict__ x, const float* __restrict__ Win,
    float* __restrict__ ext)
{
    if (blockIdx.x == 0 && blockIdx.y == 0 && threadIdx.x < 32)
        g_cnt[threadIdx.x * 32] = 0;                 // reset before recurrence

    __shared__ unsigned short Ah[64 * 40];
    __shared__ unsigned short Al[64 * 40];
    const int tid = threadIdx.x;
    const int w = tid >> 6, L = tid & 63, lh = L & 15, q = L >> 4;
    const int m0 = blockIdx.y * 64;
    const int n0 = blockIdx.x * 64 + w * 16;
    const int r_st = tid >> 2, k8 = (tid & 3) * 8;

    f32x4 acc0 = {0,0,0,0}, acc1 = {0,0,0,0}, acc2 = {0,0,0,0}, acc3 = {0,0,0,0};

    for (int kc = 0; kc < 32; ++kc){
        short8 ash, asl;
        split8(x + (size_t)(m0 + r_st) * D_DIM + kc * 32 + k8, ash, asl);
        short8 bh, bl;
        split8(Win + (size_t)(n0 + lh) * D_DIM + kc * 32 + q * 8, bh, bl);
        *(short8*)&Ah[r_st * 40 + k8] = ash;
        *(short8*)&Al[r_st * 40 + k8] = asl;
        __syncthreads();
#pragma unroll
        for (int ms = 0; ms < 4; ++ms){
            short8 ah = *(const short8*)&Ah[(ms * 16 + lh) * 40 + q * 8];
            short8 al = *(const short8*)&Al[(ms * 16 + lh) * 40 + q * 8];
            f32x4* acc = (ms == 0) ? &acc0 : (ms == 1) ? &acc1 : (ms == 2) ? &acc2 : &acc3;
            *acc = __builtin_amdgcn_mfma_f32_16x16x32_bf16(ah, bh, *acc, 0, 0, 0);
            *acc = __builtin_amdgcn_mfma_f32_16x16x32_bf16(ah, bl, *acc, 0, 0, 0);
            *acc = __builtin_amdgcn_mfma_f32_16x16x32_bf16(al, bh, *acc, 0, 0, 0);
        }
        __syncthreads();
    }

    const int col = n0 + lh;
#pragma unroll
    for (int ms = 0; ms < 4; ++ms){
        f32x4 a = (ms == 0) ? acc0 : (ms == 1) ? acc1 : (ms == 2) ? acc2 : acc3;
#pragma unroll
        for (int r = 0; r < 4; ++r){
            int row = m0 + ms * 16 + q * 4 + r;
            ext[(size_t)row * D_DIM + col] = a[r];
        }
    }
}

// ---------------- persistent recurrence: all 512 steps in one launch.
// Block j (of 32): bg = j&3 (16 batches), fblk = j>>2; wave w handles
// ft = fblk*8 + w (16 features). 512 threads, 8 waves, 72 KB LDS.
// NOTE: ext aliases out (no __restrict__ here on purpose).
__global__ __launch_bounds__(512, 1) void recurrence(
    const float* ext, const float* Wrec, float* out)
{
    __shared__ __align__(16) unsigned short st_hi[32 * 64 * 8];  // 32 KB
    __shared__ __align__(16) unsigned short st_lo[32 * 64 * 8];  // 32 KB
    __shared__ __align__(16) unsigned short tr_h[8 * 256];       // 4 KB (per-wave)
    __shared__ __align__(16) unsigned short tr_l[8 * 256];       // 4 KB

    const int tid = threadIdx.x;
    const int w = tid >> 6, L = tid & 63, lh = L & 15, q = L >> 4;
    const int j = blockIdx.x;
    const int bg = j & 3, fblk = j >> 2;
    const int ft = fblk * 8 + w;
    const int b0 = bg * 16;
    const int o  = ft * 16 + lh;
    unsigned short* trh = &tr_h[w * 256];
    unsigned short* trl = &tr_l[w * 256];
    // this wave's output tile is contiguous in the fragment-order plane.
    // ull-granule offset: shorts = bg*16384 + (ft>>1)*512 + (ft&1)*256, /4.
    const size_t toff64 = (size_t)bg * 4096 + (size_t)(ft >> 1) * 128
                        + (size_t)(ft & 1) * 64;

    // ---- pack W_rec B-fragments (hi/lo) into registers/AGPRs: 64 x short8
    short8 WH[32], WL[32];
#pragma unroll
    for (int kc = 0; kc < 32; ++kc)
        split8(Wrec + (size_t)(ft * 16 + lh) * D_DIM + kc * 32 + q * 8, WH[kc], WL[kc]);

    // ---- init: v0 = e0 -> plane 0 (transpose + coalesced agent stores)
    {
        float f[4];
#pragma unroll
        for (int r = 0; r < 4; ++r)
            f[r] = ext[(size_t)(b0 + q * 4 + r) * (TSTEPS * D_DIM) + o];
#pragma unroll
        for (int r = 0; r < 4; ++r){
            unsigned short h, l; split1(f[r], h, l);
            int s = (q * 4 + r) * 8 + ((lh >> 3) << 7) + (lh & 7);
            trh[s] = h; trl[s] = l;
        }
        asm volatile("s_waitcnt lgkmcnt(0)" ::: "memory");
        __builtin_amdgcn_sched_barrier(0);
        unsigned long long ph = *(const unsigned long long*)&trh[L * 4];
        unsigned long long pl = *(const unsigned long long*)&trl[L * 4];
        __hip_atomic_store(&g_s_hi[0][toff64 + L], ph,
                           __ATOMIC_RELAXED, __HIP_MEMORY_SCOPE_AGENT);
        __hip_atomic_store(&g_s_lo[0][toff64 + L], pl,
                           __ATOMIC_RELAXED, __HIP_MEMORY_SCOPE_AGENT);
    }
    asm volatile("" ::: "memory");          // stores strictly before prefetch

    float ev[4];                             // prefetch e_1
#pragma unroll
    for (int r = 0; r < 4; ++r)
        ev[r] = ext[(size_t)(b0 + q * 4 + r) * (TSTEPS * D_DIM) + D_DIM + o];

    asm volatile("s_waitcnt vmcnt(4)" ::: "memory");   // drain the 2 stores
    __builtin_amdgcn_s_barrier();                      // all waves' stores drained
    if (tid == 0)
        __hip_atomic_fetch_add(&g_cnt[bg * 32], 1u,
                               __ATOMIC_RELAXED, __HIP_MEMORY_SCOPE_AGENT);

#pragma unroll 1
    for (int k = 0; k < TSTEPS; ++k){
        const int p = k & 1;

        // ---- wait for state_k: wave 0 polls (8 arrivals/WG-group/round)
        if (w == 0){
            const unsigned tgt = 8u * (unsigned)(k + 1);
            for (;;){
                unsigned s = __hip_atomic_load(&g_cnt[bg * 32],
                                               __ATOMIC_RELAXED, __HIP_MEMORY_SCOPE_AGENT);
                if (s >= tgt) break;
                __builtin_amdgcn_s_sleep(2);
            }
        }
        __builtin_amdgcn_s_barrier();                  // release waves 1..7
        __builtin_amdgcn_fence(__ATOMIC_ACQUIRE, "agent");

        // ---- cooperative stage: wave w stages kc {2w,2w+1} (half A) and
        //      {16+2w,17+2w} (half B), hi+lo. 8 gl_lds16 per wave.
        const unsigned short* gh = (const unsigned short*)&g_s_hi[p][0]
                                 + (size_t)bg * 16384 + L * 8;
        const unsigned short* gl = (const unsigned short*)&g_s_lo[p][0]
                                 + (size_t)bg * 16384 + L * 8;
        {
            const int ka = 2 * w, kb = 16 + 2 * w;
            gl_lds16(gh + (size_t)ka * 512,       &st_hi[ka * 512]);
            gl_lds16(gh + (size_t)(ka + 1) * 512, &st_hi[(ka + 1) * 512]);
            gl_lds16(gl + (size_t)ka * 512,       &st_lo[ka * 512]);
            gl_lds16(gl + (size_t)(ka + 1) * 512, &st_lo[(ka + 1) * 512]);
            gl_lds16(gh + (size_t)kb * 512,       &st_hi[kb * 512]);
            gl_lds16(gh + (size_t)(kb + 1) * 512, &st_hi[(kb + 1) * 512]);
            gl_lds16(gl + (size_t)kb * 512,       &st_lo[kb * 512]);
            gl_lds16(gl + (size_t)(kb + 1) * 512, &st_lo[(kb + 1) * 512]);
        }
        // half A ready: own 4 oldest-of-8 done (plus any stale ext loads)
        asm volatile("s_waitcnt vmcnt(4)" ::: "memory");
        __builtin_amdgcn_sched_barrier(0);
        __builtin_amdgcn_s_barrier();

        f32x4 aHH = {0,0,0,0}, aHL = {0,0,0,0}, aLH = {0,0,0,0};
#pragma unroll
        for (int kc = 0; kc < 16; ++kc){
            short8 ah = *(const short8*)&st_hi[kc * 512 + L * 8];
            short8 al = *(const short8*)&st_lo[kc * 512 + L * 8];
            aHH = __builtin_amdgcn_mfma_f32_16x16x32_bf16(ah, WH[kc], aHH, 0, 0, 0);
            aHL = __builtin_amdgcn_mfma_f32_16x16x32_bf16(ah, WL[kc], aHL, 0, 0, 0);
            aLH = __builtin_amdgcn_mfma_f32_16x16x32_bf16(al, WH[kc], aLH, 0, 0, 0);
        }

        // half B ready
        asm volatile("s_waitcnt vmcnt(0)" ::: "memory");
        __builtin_amdgcn_sched_barrier(0);
        __builtin_amdgcn_s_barrier();

#pragma unroll
        for (int kc = 16; kc < 32; ++kc){
            short8 ah = *(const short8*)&st_hi[kc * 512 + L * 8];
            short8 al = *(const short8*)&st_lo[kc * 512 + L * 8];
            aHH = __builtin_amdgcn_mfma_f32_16x16x32_bf16(ah, WH[kc], aHH, 0, 0, 0);
            aHL = __builtin_amdgcn_mfma_f32_16x16x32_bf16(ah, WL[kc], aHL, 0, 0, 0);
            aLH = __builtin_amdgcn_mfma_f32_16x16x32_bf16(al, WH[kc], aLH, 0, 0, 0);
        }

        if (k == TSTEPS - 1){
            // final state -> out[:,0,:] directly, full fp32 (no bf16 trip)
#pragma unroll
            for (int r = 0; r < 4; ++r){
                int b = b0 + q * 4 + r;
                out[(size_t)b * (TSTEPS * D_DIM) + o] =
                    fmaxf(aHH[r] + aHL[r] + aLH[r], 0.f);
            }
        } else {
            const int wp = p ^ 1;
            // transpose 16x16 tile into per-wave scratch, coalesced stores
#pragma unroll
            for (int r = 0; r < 4; ++r){
                float f = fmaxf(aHH[r] + aHL[r] + aLH[r], 0.f) + ev[r];
                unsigned short h, l; split1(f, h, l);
                int s = (q * 4 + r) * 8 + ((lh >> 3) << 7) + (lh & 7);
                trh[s] = h; trl[s] = l;
            }
            asm volatile("s_waitcnt lgkmcnt(0)" ::: "memory");
            __builtin_amdgcn_sched_barrier(0);
            {
                unsigned long long ph = *(const unsigned long long*)&trh[L * 4];
                unsigned long long pl = *(const unsigned long long*)&trl[L * 4];
                __hip_atomic_store(&g_s_hi[wp][toff64 + L], ph,
                                   __ATOMIC_RELAXED, __HIP_MEMORY_SCOPE_AGENT);
                __hip_atomic_store(&g_s_lo[wp][toff64 + L], pl,
                                   __ATOMIC_RELAXED, __HIP_MEMORY_SCOPE_AGENT);
            }
            asm volatile("" ::: "memory");  // stores strictly before prefetch
            if (k + 2 < TSTEPS){
                // prefetch e_{k+2}; latency hides under the next barrier wait
#pragma unroll
                for (int r = 0; r < 4; ++r)
                    ev[r] = ext[(size_t)(b0 + q * 4 + r) * (TSTEPS * D_DIM)
                                + (size_t)(k + 2) * D_DIM + o];
                asm volatile("s_waitcnt vmcnt(4)" ::: "memory");  // 2 stores drained
            } else {
                asm volatile("s_waitcnt vmcnt(0)" ::: "memory");
            }
            __builtin_amdgcn_s_barrier();       // all waves' stores drained
            if (tid == 0)
                __hip_atomic_fetch_add(&g_cnt[bg * 32], 1u,
                                       __ATOMIC_RELAXED, __HIP_MEMORY_SCOPE_AGENT);
        }
    }
}

// ---------------- out[:,1:,:] = 0 (out[:,0,:] holds the final state)
__global__ __launch_bounds__(256) void zero_rest(float* __restrict__ out)
{
    size_t i4 = (size_t)blockIdx.x * 256 + threadIdx.x;  // float4 index
    size_t f = i4 * 4;
    int t = (int)((f >> 10) & 511);
    if (t == 0) return;                                   // out[:,0,:] kept
    *(float4*)(out + f) = make_float4(0.f, 0.f, 0.f, 0.f);
}

extern "C" void kernel_launch(void* const* d_in, const int* in_sizes, int n_in,
                              void* d_out, int out_size, void* d_ws, size_t ws_size,
                              hipStream_t stream) {
    const float* x     = (const float*)d_in[0];   // [64][512][1024]
    const float* W_in  = (const float*)d_in[1];   // [1024][1024]
    const float* W_rec = (const float*)d_in[2];   // [1024][1024]
    float* out = (float*)d_out;

    // ext (fp32, [b][t][o]) lives in d_out — dead space until the end.
    float* ext = out;

    // 1) input projection (+ resets barrier counters for this replay)
    ext_gemm<<<dim3(16, 512), 256, 0, stream>>>(x, W_in, ext);

    // 2) all 512 recurrence steps in ONE persistent kernel (32 WGs x 512 thr)
    recurrence<<<32, 512, 0, stream>>>(ext, W_rec, out);

    // 3) zero everything except out[:,0,:]
    zero_rest<<<32768, 256, 0, stream>>>(out);
}

// Round 6
// 3158.210 us; speedup vs baseline: 1.7799x; 1.7799x over previous
//
#include <hip/hip_runtime.h>

typedef __attribute__((ext_vector_type(8))) short short8;
typedef __attribute__((ext_vector_type(4))) float f32x4;

#define D_DIM 1024
#define BS 64
#define TSTEPS 512

// ---------------------------------------------------------------------------
// R6: persistent recurrence, 4-wave workgroups (256 thr), 64 WGs.
//   R5's 8-wave WG halved the per-wave reg budget (2 waves/SIMD -> 256) and
//   spilled the 256-reg weight block to scratch (VGPR_Count 176->128, 2x
//   slower). 4 waves/WG = 1 wave/SIMD -> full 512-reg budget, weights stay
//   in AGPRs (as R4), while keeping R5's sync/staging wins:
//   - arrivals per group per step: 16 (was 64 in R4); one line per group;
//     wave 0 polls, waves 1-3 released by HW s_barrier.
//   - slab staged cooperatively ONCE per WG (4 MB/step LLC burst, was 16).
//     Two halves gated by counted vmcnt(8)/vmcnt(0) so fill overlaps MFMA.
//   - per-wave math identical to R4 -> bit-identical numerics.
// ---------------------------------------------------------------------------

// state planes: [plane][bg(4)][kc(32)][lane(64)][8 bf16] hi / lo.
// Declared as ull (4 shorts each) so 8B agent atomic stores are well-typed.
__device__ __align__(16) unsigned long long g_s_hi[2][16384];  // 2 x 128 KB
__device__ __align__(16) unsigned long long g_s_lo[2][16384];
// per-group barrier counters: g_cnt[bg*32], one 128B line per group
__device__ unsigned g_cnt[4 * 8 * 32];

__device__ __forceinline__ unsigned short f2bf(float f){
    union { float f; unsigned u; } v; v.f = f;
    unsigned r = v.u + 0x7FFFu + ((v.u >> 16) & 1u);   // RNE
    return (unsigned short)(r >> 16);
}
__device__ __forceinline__ float bf2f(unsigned short h){
    union { unsigned u; float f; } v; v.u = ((unsigned)h) << 16;
    return v.f;
}
__device__ __forceinline__ void split1(float f, unsigned short& h, unsigned short& l){
    h = f2bf(f);
    l = f2bf(f - bf2f(h));
}
__device__ __forceinline__ void split8(const float* __restrict__ p, short8& h8, short8& l8){
    float4 f0 = *(const float4*)p;
    float4 f1 = *(const float4*)(p + 4);
    float v[8] = {f0.x, f0.y, f0.z, f0.w, f1.x, f1.y, f1.z, f1.w};
#pragma unroll
    for (int i = 0; i < 8; ++i){
        unsigned short h, l; split1(v[i], h, l);
        h8[i] = (short)h; l8[i] = (short)l;
    }
}

// async 16B global->LDS (per-lane src, linear wave dest = base + lane*16)
__device__ __forceinline__ void gl_lds16(const unsigned short* g, unsigned short* l){
    __builtin_amdgcn_global_load_lds(
        (__attribute__((address_space(1))) void*)(unsigned long long)(g),
        (__attribute__((address_space(3))) void*)(unsigned int)(unsigned long long)(l),
        16, 0, 0);
}

// ---------------- ext[r][o] = sum_j x[r][j]*Win[o][j], fp32, r = b*512+t.
// Unchanged numerics; also resets the barrier-counter lines each replay.
__global__ __launch_bounds__(256) void ext_gemm(
    const float* __restrict__ x, const float* __restrict__ Win,
    float* __restrict__ ext)
{
    if (blockIdx.x == 0 && blockIdx.y == 0 && threadIdx.x < 32)
        g_cnt[threadIdx.x * 32] = 0;                 // reset before recurrence

    __shared__ unsigned short Ah[64 * 40];
    __shared__ unsigned short Al[64 * 40];
    const int tid = threadIdx.x;
    const int w = tid >> 6, L = tid & 63, lh = L & 15, q = L >> 4;
    const int m0 = blockIdx.y * 64;
    const int n0 = blockIdx.x * 64 + w * 16;
    const int r_st = tid >> 2, k8 = (tid & 3) * 8;

    f32x4 acc0 = {0,0,0,0}, acc1 = {0,0,0,0}, acc2 = {0,0,0,0}, acc3 = {0,0,0,0};

    for (int kc = 0; kc < 32; ++kc){
        short8 ash, asl;
        split8(x + (size_t)(m0 + r_st) * D_DIM + kc * 32 + k8, ash, asl);
        short8 bh, bl;
        split8(Win + (size_t)(n0 + lh) * D_DIM + kc * 32 + q * 8, bh, bl);
        *(short8*)&Ah[r_st * 40 + k8] = ash;
        *(short8*)&Al[r_st * 40 + k8] = asl;
        __syncthreads();
#pragma unroll
        for (int ms = 0; ms < 4; ++ms){
            short8 ah = *(const short8*)&Ah[(ms * 16 + lh) * 40 + q * 8];
            short8 al = *(const short8*)&Al[(ms * 16 + lh) * 40 + q * 8];
            f32x4* acc = (ms == 0) ? &acc0 : (ms == 1) ? &acc1 : (ms == 2) ? &acc2 : &acc3;
            *acc = __builtin_amdgcn_mfma_f32_16x16x32_bf16(ah, bh, *acc, 0, 0, 0);
            *acc = __builtin_amdgcn_mfma_f32_16x16x32_bf16(ah, bl, *acc, 0, 0, 0);
            *acc = __builtin_amdgcn_mfma_f32_16x16x32_bf16(al, bh, *acc, 0, 0, 0);
        }
        __syncthreads();
    }

    const int col = n0 + lh;
#pragma unroll
    for (int ms = 0; ms < 4; ++ms){
        f32x4 a = (ms == 0) ? acc0 : (ms == 1) ? acc1 : (ms == 2) ? acc2 : acc3;
#pragma unroll
        for (int r = 0; r < 4; ++r){
            int row = m0 + ms * 16 + q * 4 + r;
            ext[(size_t)row * D_DIM + col] = a[r];
        }
    }
}

// ---------------- persistent recurrence: all 512 steps in one launch.
// Block j (of 64): bg = j&3 (16 batches), fblk = j>>2 (of 16); wave w
// handles ft = fblk*4 + w (16 features). 256 threads, 4 waves, 68 KB LDS.
// NOTE: ext aliases out (no __restrict__ here on purpose).
__global__ __launch_bounds__(256, 1) void recurrence(
    const float* ext, const float* Wrec, float* out)
{
    __shared__ __align__(16) unsigned short st_hi[32 * 64 * 8];  // 32 KB
    __shared__ __align__(16) unsigned short st_lo[32 * 64 * 8];  // 32 KB
    __shared__ __align__(16) unsigned short tr_h[4 * 256];       // 2 KB (per-wave)
    __shared__ __align__(16) unsigned short tr_l[4 * 256];       // 2 KB

    const int tid = threadIdx.x;
    const int w = tid >> 6, L = tid & 63, lh = L & 15, q = L >> 4;
    const int j = blockIdx.x;
    const int bg = j & 3, fblk = j >> 2;
    const int ft = fblk * 4 + w;
    const int b0 = bg * 16;
    const int o  = ft * 16 + lh;
    unsigned short* trh = &tr_h[w * 256];
    unsigned short* trl = &tr_l[w * 256];
    // this wave's output tile is contiguous in the fragment-order plane.
    // ull-granule offset: shorts = bg*16384 + (ft>>1)*512 + (ft&1)*256, /4.
    const size_t toff64 = (size_t)bg * 4096 + (size_t)(ft >> 1) * 128
                        + (size_t)(ft & 1) * 64;

    // ---- pack W_rec B-fragments (hi/lo) into AGPRs: 64 x short8 = 256 regs
    short8 WH[32], WL[32];
#pragma unroll
    for (int kc = 0; kc < 32; ++kc)
        split8(Wrec + (size_t)(ft * 16 + lh) * D_DIM + kc * 32 + q * 8, WH[kc], WL[kc]);

    // ---- init: v0 = e0 -> plane 0 (transpose + coalesced agent stores)
    {
        float f[4];
#pragma unroll
        for (int r = 0; r < 4; ++r)
            f[r] = ext[(size_t)(b0 + q * 4 + r) * (TSTEPS * D_DIM) + o];
#pragma unroll
        for (int r = 0; r < 4; ++r){
            unsigned short h, l; split1(f[r], h, l);
            int s = (q * 4 + r) * 8 + ((lh >> 3) << 7) + (lh & 7);
            trh[s] = h; trl[s] = l;
        }
        asm volatile("s_waitcnt lgkmcnt(0)" ::: "memory");
        __builtin_amdgcn_sched_barrier(0);
        unsigned long long ph = *(const unsigned long long*)&trh[L * 4];
        unsigned long long pl = *(const unsigned long long*)&trl[L * 4];
        __hip_atomic_store(&g_s_hi[0][toff64 + L], ph,
                           __ATOMIC_RELAXED, __HIP_MEMORY_SCOPE_AGENT);
        __hip_atomic_store(&g_s_lo[0][toff64 + L], pl,
                           __ATOMIC_RELAXED, __HIP_MEMORY_SCOPE_AGENT);
    }
    asm volatile("" ::: "memory");          // stores strictly before prefetch

    float ev[4];                             // prefetch e_1
#pragma unroll
    for (int r = 0; r < 4; ++r)
        ev[r] = ext[(size_t)(b0 + q * 4 + r) * (TSTEPS * D_DIM) + D_DIM + o];

    asm volatile("s_waitcnt vmcnt(4)" ::: "memory");   // drain the 2 stores
    __builtin_amdgcn_s_barrier();                      // all waves' stores drained
    if (tid == 0)
        __hip_atomic_fetch_add(&g_cnt[bg * 32], 1u,
                               __ATOMIC_RELAXED, __HIP_MEMORY_SCOPE_AGENT);

#pragma unroll 1
    for (int k = 0; k < TSTEPS; ++k){
        const int p = k & 1;

        // ---- wait for state_k: wave 0 polls (16 arrivals/group/round)
        if (w == 0){
            const unsigned tgt = 16u * (unsigned)(k + 1);
            for (;;){
                unsigned s = __hip_atomic_load(&g_cnt[bg * 32],
                                               __ATOMIC_RELAXED, __HIP_MEMORY_SCOPE_AGENT);
                if (s >= tgt) break;
                __builtin_amdgcn_s_sleep(2);
            }
        }
        __builtin_amdgcn_s_barrier();                  // release waves 1..3
        __builtin_amdgcn_fence(__ATOMIC_ACQUIRE, "agent");

        // ---- cooperative stage: wave w stages kc {4w..4w+3} (half A, 8
        //      loads hi+lo) then {16+4w..19+4w} (half B, 8 loads).
        const unsigned short* gh = (const unsigned short*)&g_s_hi[p][0]
                                 + (size_t)bg * 16384 + L * 8;
        const unsigned short* gl = (const unsigned short*)&g_s_lo[p][0]
                                 + (size_t)bg * 16384 + L * 8;
        {
            const int ka = 4 * w, kb = 16 + 4 * w;
#pragma unroll
            for (int i = 0; i < 4; ++i)
                gl_lds16(gh + (size_t)(ka + i) * 512, &st_hi[(ka + i) * 512]);
#pragma unroll
            for (int i = 0; i < 4; ++i)
                gl_lds16(gl + (size_t)(ka + i) * 512, &st_lo[(ka + i) * 512]);
#pragma unroll
            for (int i = 0; i < 4; ++i)
                gl_lds16(gh + (size_t)(kb + i) * 512, &st_hi[(kb + i) * 512]);
#pragma unroll
            for (int i = 0; i < 4; ++i)
                gl_lds16(gl + (size_t)(kb + i) * 512, &st_lo[(kb + i) * 512]);
        }
        // half A ready: own 8 oldest (after <=4 ev loads) done when <=8 remain
        asm volatile("s_waitcnt vmcnt(8)" ::: "memory");
        __builtin_amdgcn_sched_barrier(0);
        __builtin_amdgcn_s_barrier();

        f32x4 aHH = {0,0,0,0}, aHL = {0,0,0,0}, aLH = {0,0,0,0};
#pragma unroll
        for (int kc = 0; kc < 16; ++kc){
            short8 ah = *(const short8*)&st_hi[kc * 512 + L * 8];
            short8 al = *(const short8*)&st_lo[kc * 512 + L * 8];
            aHH = __builtin_amdgcn_mfma_f32_16x16x32_bf16(ah, WH[kc], aHH, 0, 0, 0);
            aHL = __builtin_amdgcn_mfma_f32_16x16x32_bf16(ah, WL[kc], aHL, 0, 0, 0);
            aLH = __builtin_amdgcn_mfma_f32_16x16x32_bf16(al, WH[kc], aLH, 0, 0, 0);
        }

        // half B ready
        asm volatile("s_waitcnt vmcnt(0)" ::: "memory");
        __builtin_amdgcn_sched_barrier(0);
        __builtin_amdgcn_s_barrier();

#pragma unroll
        for (int kc = 16; kc < 32; ++kc){
            short8 ah = *(const short8*)&st_hi[kc * 512 + L * 8];
            short8 al = *(const short8*)&st_lo[kc * 512 + L * 8];
            aHH = __builtin_amdgcn_mfma_f32_16x16x32_bf16(ah, WH[kc], aHH, 0, 0, 0);
            aHL = __builtin_amdgcn_mfma_f32_16x16x32_bf16(ah, WL[kc], aHL, 0, 0, 0);
            aLH = __builtin_amdgcn_mfma_f32_16x16x32_bf16(al, WH[kc], aLH, 0, 0, 0);
        }

        if (k == TSTEPS - 1){
            // final state -> out[:,0,:] directly, full fp32 (no bf16 trip)
#pragma unroll
            for (int r = 0; r < 4; ++r){
                int b = b0 + q * 4 + r;
                out[(size_t)b * (TSTEPS * D_DIM) + o] =
                    fmaxf(aHH[r] + aHL[r] + aLH[r], 0.f);
            }
        } else {
            const int wp = p ^ 1;
            // transpose 16x16 tile into per-wave scratch, coalesced stores
#pragma unroll
            for (int r = 0; r < 4; ++r){
                float f = fmaxf(aHH[r] + aHL[r] + aLH[r], 0.f) + ev[r];
                unsigned short h, l; split1(f, h, l);
                int s = (q * 4 + r) * 8 + ((lh >> 3) << 7) + (lh & 7);
                trh[s] = h; trl[s] = l;
            }
            asm volatile("s_waitcnt lgkmcnt(0)" ::: "memory");
            __builtin_amdgcn_sched_barrier(0);
            {
                unsigned long long ph = *(const unsigned long long*)&trh[L * 4];
                unsigned long long pl = *(const unsigned long long*)&trl[L * 4];
                __hip_atomic_store(&g_s_hi[wp][toff64 + L], ph,
                                   __ATOMIC_RELAXED, __HIP_MEMORY_SCOPE_AGENT);
                __hip_atomic_store(&g_s_lo[wp][toff64 + L], pl,
                                   __ATOMIC_RELAXED, __HIP_MEMORY_SCOPE_AGENT);
            }
            asm volatile("" ::: "memory");  // stores strictly before prefetch
            if (k + 2 < TSTEPS){
                // prefetch e_{k+2}; latency hides under the next barrier wait
#pragma unroll
                for (int r = 0; r < 4; ++r)
                    ev[r] = ext[(size_t)(b0 + q * 4 + r) * (TSTEPS * D_DIM)
                                + (size_t)(k + 2) * D_DIM + o];
                asm volatile("s_waitcnt vmcnt(4)" ::: "memory");  // 2 stores drained
            } else {
                asm volatile("s_waitcnt vmcnt(0)" ::: "memory");
            }
            __builtin_amdgcn_s_barrier();       // all waves' stores drained
            if (tid == 0)
                __hip_atomic_fetch_add(&g_cnt[bg * 32], 1u,
                                       __ATOMIC_RELAXED, __HIP_MEMORY_SCOPE_AGENT);
        }
    }
}

// ---------------- out[:,1:,:] = 0 (out[:,0,:] holds the final state)
__global__ __launch_bounds__(256) void zero_rest(float* __restrict__ out)
{
    size_t i4 = (size_t)blockIdx.x * 256 + threadIdx.x;  // float4 index
    size_t f = i4 * 4;
    int t = (int)((f >> 10) & 511);
    if (t == 0) return;                                   // out[:,0,:] kept
    *(float4*)(out + f) = make_float4(0.f, 0.f, 0.f, 0.f);
}

extern "C" void kernel_launch(void* const* d_in, const int* in_sizes, int n_in,
                              void* d_out, int out_size, void* d_ws, size_t ws_size,
                              hipStream_t stream) {
    const float* x     = (const float*)d_in[0];   // [64][512][1024]
    const float* W_in  = (const float*)d_in[1];   // [1024][1024]
    const float* W_rec = (const float*)d_in[2];   // [1024][1024]
    float* out = (float*)d_out;

    // ext (fp32, [b][t][o]) lives in d_out — dead space until the end.
    float* ext = out;

    // 1) input projection (+ resets barrier counters for this replay)
    ext_gemm<<<dim3(16, 512), 256, 0, stream>>>(x, W_in, ext);

    // 2) all 512 recurrence steps in ONE persistent kernel (64 WGs x 256 thr)
    recurrence<<<64, 256, 0, stream>>>(ext, W_rec, out);

    // 3) zero everything except out[:,0,:]
    zero_rest<<<32768, 256, 0, stream>>>(out);
}

// Round 7
// 2526.487 us; speedup vs baseline: 2.2249x; 1.2500x over previous
//
#include <hip/hip_runtime.h>

typedef __attribute__((ext_vector_type(8))) short short8;
typedef __attribute__((ext_vector_type(4))) float f32x4;
typedef __attribute__((ext_vector_type(4))) unsigned int u32x4;

#define D_DIM 1024
#define BS 64
#define TSTEPS 512

// ---------------------------------------------------------------------------
// R7: persistent recurrence, fence-free LLC handoff.
//   R6 post-mortem: arrival count and staging volume were not the bottleneck;
//   the serial chain is LLC-coherence machinery (per-step agent-acquire fence
//   = full L2 invalidation on every consumer WG, + 16 same-line atomic RMWs).
//   Changes:
//   - NO acquire fence. Staging global_load_lds uses aux=17 (sc0|sc1): reads
//     bypass L1+L2 and snoop the LLC directly, where producer stores (also
//     sc0|sc1, = agent-relaxed store semantics) landed before the flag add.
//   - Fused hi/lo state layout [plane][bg][kc][lane][hi8|lo8]: producer tile
//     is 1KB contiguous -> ONE 16B store per lane (asm global_store_dwordx4
//     sc0 sc1; also sidesteps -Watomic-alignment).
//   - Arrival counters sharded x4 per group; poller reads 4 shards with one
//     lane-parallel load + 2 shfl_xor.
//   - Same WG shape as R6 (4 waves, 256 thr, 64 WGs), weights in AGPRs,
//     kc order unchanged -> bit-identical numerics.
// ---------------------------------------------------------------------------

// fused state planes: [plane(2)][bg(4)][kc(32)][lane(64)][hi8|lo8] bf16
// byte offset = plane*262144 + bg*65536 + kc*2048 + lane*32 + half*16
__device__ __align__(16) unsigned int g_s[2][65536];   // 512 KB total
// per-group sharded barrier counters: [bg(4)][shard(4)] one 128B line each
__device__ unsigned g_cnt[4 * 4 * 32];

__device__ __forceinline__ unsigned short f2bf(float f){
    union { float f; unsigned u; } v; v.f = f;
    unsigned r = v.u + 0x7FFFu + ((v.u >> 16) & 1u);   // RNE
    return (unsigned short)(r >> 16);
}
__device__ __forceinline__ float bf2f(unsigned short h){
    union { unsigned u; float f; } v; v.u = ((unsigned)h) << 16;
    return v.f;
}
__device__ __forceinline__ void split1(float f, unsigned short& h, unsigned short& l){
    h = f2bf(f);
    l = f2bf(f - bf2f(h));
}
__device__ __forceinline__ void split8(const float* __restrict__ p, short8& h8, short8& l8){
    float4 f0 = *(const float4*)p;
    float4 f1 = *(const float4*)(p + 4);
    float v[8] = {f0.x, f0.y, f0.z, f0.w, f1.x, f1.y, f1.z, f1.w};
#pragma unroll
    for (int i = 0; i < 8; ++i){
        unsigned short h, l; split1(v[i], h, l);
        h8[i] = (short)h; l8[i] = (short)l;
    }
}

// async 16B global->LDS, LLC-coherent (aux=17: sc0|sc1 -> bypass L1+L2)
__device__ __forceinline__ void gl_lds16_llc(const void* g, void* l){
    __builtin_amdgcn_global_load_lds(
        (const __attribute__((address_space(1))) void*)(unsigned long long)(uintptr_t)g,
        (__attribute__((address_space(3))) void*)(unsigned int)(unsigned long long)(uintptr_t)l,
        16, 0, 17);
}

// 16B store straight to the LLC (sc0 sc1 = agent-relaxed store semantics)
__device__ __forceinline__ void store16_llc(void* g, u32x4 v){
    asm volatile("global_store_dwordx4 %0, %1, off sc0 sc1"
                 :: "v"((unsigned long long)(uintptr_t)g), "v"(v) : "memory");
}

// ---------------- ext[r][o] = sum_j x[r][j]*Win[o][j], fp32, r = b*512+t.
// Unchanged numerics; also resets the 16 barrier-counter lines each replay.
__global__ __launch_bounds__(256) void ext_gemm(
    const float* __restrict__ x, const float* __restrict__ Win,
    float* __restrict__ ext)
{
    if (blockIdx.x == 0 && blockIdx.y == 0 && threadIdx.x < 16)
        g_cnt[threadIdx.x * 32] = 0;                 // reset before recurrence

    __shared__ unsigned short Ah[64 * 40];
    __shared__ unsigned short Al[64 * 40];
    const int tid = threadIdx.x;
    const int w = tid >> 6, L = tid & 63, lh = L & 15, q = L >> 4;
    const int m0 = blockIdx.y * 64;
    const int n0 = blockIdx.x * 64 + w * 16;
    const int r_st = tid >> 2, k8 = (tid & 3) * 8;

    f32x4 acc0 = {0,0,0,0}, acc1 = {0,0,0,0}, acc2 = {0,0,0,0}, acc3 = {0,0,0,0};

    for (int kc = 0; kc < 32; ++kc){
        short8 ash, asl;
        split8(x + (size_t)(m0 + r_st) * D_DIM + kc * 32 + k8, ash, asl);
        short8 bh, bl;
        split8(Win + (size_t)(n0 + lh) * D_DIM + kc * 32 + q * 8, bh, bl);
        *(short8*)&Ah[r_st * 40 + k8] = ash;
        *(short8*)&Al[r_st * 40 + k8] = asl;
        __syncthreads();
#pragma unroll
        for (int ms = 0; ms < 4; ++ms){
            short8 ah = *(const short8*)&Ah[(ms * 16 + lh) * 40 + q * 8];
            short8 al = *(const short8*)&Al[(ms * 16 + lh) * 40 + q * 8];
            f32x4* acc = (ms == 0) ? &acc0 : (ms == 1) ? &acc1 : (ms == 2) ? &acc2 : &acc3;
            *acc = __builtin_amdgcn_mfma_f32_16x16x32_bf16(ah, bh, *acc, 0, 0, 0);
            *acc = __builtin_amdgcn_mfma_f32_16x16x32_bf16(ah, bl, *acc, 0, 0, 0);
            *acc = __builtin_amdgcn_mfma_f32_16x16x32_bf16(al, bh, *acc, 0, 0, 0);
        }
        __syncthreads();
    }

    const int col = n0 + lh;
#pragma unroll
    for (int ms = 0; ms < 4; ++ms){
        f32x4 a = (ms == 0) ? acc0 : (ms == 1) ? acc1 : (ms == 2) ? acc2 : acc3;
#pragma unroll
        for (int r = 0; r < 4; ++r){
            int row = m0 + ms * 16 + q * 4 + r;
            ext[(size_t)row * D_DIM + col] = a[r];
        }
    }
}

// ---------------- persistent recurrence: all 512 steps in one launch.
// Block j (of 64): bg = j&3 (16 batches), fblk = j>>2 (of 16); wave w
// handles ft = fblk*4 + w (16 features). 256 threads, 4 waves, 68 KB LDS.
// NOTE: ext aliases out (no __restrict__ here on purpose).
__global__ __launch_bounds__(256, 1) void recurrence(
    const float* ext, const float* Wrec, float* out)
{
    // LDS state slab: [kc(32)][plane(2: hi,lo)][lane(64)][8] = 64 KB
    __shared__ __align__(16) unsigned short st[32 * 1024];
    // per-wave transpose scratch: [wave][hi 256 | lo 256] shorts = 4 KB
    __shared__ __align__(16) unsigned short tr[4][512];

    const int tid = threadIdx.x;
    const int w = tid >> 6, L = tid & 63, lh = L & 15, q = L >> 4;
    const int j = blockIdx.x;
    const int bg = j & 3, fblk = j >> 2;
    const int ft = fblk * 4 + w;
    const int b0 = bg * 16;
    const int o  = ft * 16 + lh;
    unsigned short* trh = &tr[w][0];
    unsigned short* trl = &tr[w][256];
    char* const gsb = (char*)&g_s[0][0];
    // producer tile: 1 KB contiguous at kct*2048 + (ft&1)*1024 within the slab
    const size_t tbyte = (size_t)bg * 65536 + (size_t)(ft >> 1) * 2048
                       + (size_t)(ft & 1) * 1024
                       + (size_t)(L & 31) * 32 + (size_t)(L >> 5) * 16;
    // per-lane 16B source in transpose scratch (lanes 0-31: hi, 32-63: lo)
    const int troff = (L >> 5) * 256 + (L & 31) * 8;

    // ---- pack W_rec B-fragments (hi/lo) into AGPRs: 64 x short8 = 256 regs
    short8 WH[32], WL[32];
#pragma unroll
    for (int kc = 0; kc < 32; ++kc)
        split8(Wrec + (size_t)(ft * 16 + lh) * D_DIM + kc * 32 + q * 8, WH[kc], WL[kc]);

    // ---- init: v0 = e0 -> plane 0 (transpose + one 16B LLC store per lane)
    {
        float f[4];
#pragma unroll
        for (int r = 0; r < 4; ++r)
            f[r] = ext[(size_t)(b0 + q * 4 + r) * (TSTEPS * D_DIM) + o];
#pragma unroll
        for (int r = 0; r < 4; ++r){
            unsigned short h, l; split1(f[r], h, l);
            int s = (q * 4 + r) * 8 + ((lh >> 3) << 7) + (lh & 7);
            trh[s] = h; trl[s] = l;
        }
        asm volatile("s_waitcnt lgkmcnt(0)" ::: "memory");
        __builtin_amdgcn_sched_barrier(0);
        u32x4 val = *(const u32x4*)&tr[w][troff];
        store16_llc(gsb + tbyte, val);
    }

    float ev[4];                             // prefetch e_1
#pragma unroll
    for (int r = 0; r < 4; ++r)
        ev[r] = ext[(size_t)(b0 + q * 4 + r) * (TSTEPS * D_DIM) + D_DIM + o];

    asm volatile("s_waitcnt vmcnt(4)" ::: "memory");   // drain the 1 store
    __builtin_amdgcn_s_barrier();                      // all waves' stores drained
    if (tid == 0)
        __hip_atomic_fetch_add(&g_cnt[(bg * 4 + (fblk & 3)) * 32], 1u,
                               __ATOMIC_RELAXED, __HIP_MEMORY_SCOPE_AGENT);

#pragma unroll 1
    for (int k = 0; k < TSTEPS; ++k){
        const int p = k & 1;

        // ---- wait for state_k: wave 0 polls 4 shards lane-parallel
        if (w == 0){
            const unsigned tgt = 16u * (unsigned)(k + 1);
            const unsigned* cl = &g_cnt[(bg * 4 + (L & 3)) * 32];
            for (;;){
                unsigned s = __hip_atomic_load(cl, __ATOMIC_RELAXED,
                                               __HIP_MEMORY_SCOPE_AGENT);
                s += __shfl_xor(s, 1);
                s += __shfl_xor(s, 2);
                if (s >= tgt) break;
                __builtin_amdgcn_s_sleep(1);
            }
        }
        __builtin_amdgcn_s_barrier();                  // release waves 1..3
        asm volatile("" ::: "memory");                 // staging stays below

        // ---- cooperative stage (LLC-coherent, no fence needed):
        // wave w: kc {4w..4w+3} (half A) then {16+4w..19+4w} (half B).
        const char* gb = gsb + (size_t)p * 262144 + (size_t)bg * 65536;
        {
            const int ka = 4 * w, kb = 16 + 4 * w;
#pragma unroll
            for (int i = 0; i < 4; ++i){
                gl_lds16_llc(gb + (size_t)(ka + i) * 2048 + L * 32,
                             &st[(ka + i) * 1024 + L * 8]);
                gl_lds16_llc(gb + (size_t)(ka + i) * 2048 + L * 32 + 16,
                             &st[(ka + i) * 1024 + 512 + L * 8]);
            }
#pragma unroll
            for (int i = 0; i < 4; ++i){
                gl_lds16_llc(gb + (size_t)(kb + i) * 2048 + L * 32,
                             &st[(kb + i) * 1024 + L * 8]);
                gl_lds16_llc(gb + (size_t)(kb + i) * 2048 + L * 32 + 16,
                             &st[(kb + i) * 1024 + 512 + L * 8]);
            }
        }
        // half A ready: own 8 oldest done (after <=4 stale ev loads drain)
        asm volatile("s_waitcnt vmcnt(8)" ::: "memory");
        __builtin_amdgcn_sched_barrier(0);
        __builtin_amdgcn_s_barrier();

        f32x4 aHH = {0,0,0,0}, aHL = {0,0,0,0}, aLH = {0,0,0,0};
#pragma unroll
        for (int kc = 0; kc < 16; ++kc){
            short8 ah = *(const short8*)&st[kc * 1024 + L * 8];
            short8 al = *(const short8*)&st[kc * 1024 + 512 + L * 8];
            aHH = __builtin_amdgcn_mfma_f32_16x16x32_bf16(ah, WH[kc], aHH, 0, 0, 0);
            aHL = __builtin_amdgcn_mfma_f32_16x16x32_bf16(ah, WL[kc], aHL, 0, 0, 0);
            aLH = __builtin_amdgcn_mfma_f32_16x16x32_bf16(al, WH[kc], aLH, 0, 0, 0);
        }

        // half B ready
        asm volatile("s_waitcnt vmcnt(0)" ::: "memory");
        __builtin_amdgcn_sched_barrier(0);
        __builtin_amdgcn_s_barrier();

#pragma unroll
        for (int kc = 16; kc < 32; ++kc){
            short8 ah = *(const short8*)&st[kc * 1024 + L * 8];
            short8 al = *(const short8*)&st[kc * 1024 + 512 + L * 8];
            aHH = __builtin_amdgcn_mfma_f32_16x16x32_bf16(ah, WH[kc], aHH, 0, 0, 0);
            aHL = __builtin_amdgcn_mfma_f32_16x16x32_bf16(ah, WL[kc], aHL, 0, 0, 0);
            aLH = __builtin_amdgcn_mfma_f32_16x16x32_bf16(al, WH[kc], aLH, 0, 0, 0);
        }

        if (k == TSTEPS - 1){
            // final state -> out[:,0,:] directly, full fp32 (no bf16 trip)
#pragma unroll
            for (int r = 0; r < 4; ++r){
                int b = b0 + q * 4 + r;
                out[(size_t)b * (TSTEPS * D_DIM) + o] =
                    fmaxf(aHH[r] + aHL[r] + aLH[r], 0.f);
            }
        } else {
            const int wp = p ^ 1;
            // transpose 16x16 tile into per-wave scratch, one 16B store/lane
#pragma unroll
            for (int r = 0; r < 4; ++r){
                float f = fmaxf(aHH[r] + aHL[r] + aLH[r], 0.f) + ev[r];
                unsigned short h, l; split1(f, h, l);
                int s = (q * 4 + r) * 8 + ((lh >> 3) << 7) + (lh & 7);
                trh[s] = h; trl[s] = l;
            }
            asm volatile("s_waitcnt lgkmcnt(0)" ::: "memory");
            __builtin_amdgcn_sched_barrier(0);
            {
                u32x4 val = *(const u32x4*)&tr[w][troff];
                store16_llc(gsb + (size_t)wp * 262144 + tbyte, val);
            }
            asm volatile("" ::: "memory");  // store strictly before prefetch
            if (k + 2 < TSTEPS){
                // prefetch e_{k+2}; latency hides under the next barrier wait
#pragma unroll
                for (int r = 0; r < 4; ++r)
                    ev[r] = ext[(size_t)(b0 + q * 4 + r) * (TSTEPS * D_DIM)
                                + (size_t)(k + 2) * D_DIM + o];
                asm volatile("s_waitcnt vmcnt(4)" ::: "memory");  // store drained
            } else {
                asm volatile("s_waitcnt vmcnt(0)" ::: "memory");
            }
            __builtin_amdgcn_s_barrier();       // all waves' stores drained
            if (tid == 0)
                __hip_atomic_fetch_add(&g_cnt[(bg * 4 + (fblk & 3)) * 32], 1u,
                                       __ATOMIC_RELAXED, __HIP_MEMORY_SCOPE_AGENT);
        }
    }
}

// ---------------- out[:,1:,:] = 0 (out[:,0,:] holds the final state)
__global__ __launch_bounds__(256) void zero_rest(float* __restrict__ out)
{
    size_t i4 = (size_t)blockIdx.x * 256 + threadIdx.x;  // float4 index
    size_t f = i4 * 4;
    int t = (int)((f >> 10) & 511);
    if (t == 0) return;                                   // out[:,0,:] kept
    *(float4*)(out + f) = make_float4(0.f, 0.f, 0.f, 0.f);
}

extern "C" void kernel_launch(void* const* d_in, const int* in_sizes, int n_in,
                              void* d_out, int out_size, void* d_ws, size_t ws_size,
                              hipStream_t stream) {
    const float* x     = (const float*)d_in[0];   // [64][512][1024]
    const float* W_in  = (const float*)d_in[1];   // [1024][1024]
    const float* W_rec = (const float*)d_in[2];   // [1024][1024]
    float* out = (float*)d_out;

    // ext (fp32, [b][t][o]) lives in d_out — dead space until the end.
    float* ext = out;

    // 1) input projection (+ resets barrier counters for this replay)
    ext_gemm<<<dim3(16, 512), 256, 0, stream>>>(x, W_in, ext);

    // 2) all 512 recurrence steps in ONE persistent kernel (64 WGs x 256 thr)
    recurrence<<<64, 256, 0, stream>>>(ext, W_rec, out);

    // 3) zero everything except out[:,0,:]
    zero_rest<<<32768, 256, 0, stream>>>(out);
}

// Round 8
// 2495.444 us; speedup vs baseline: 2.2526x; 1.0124x over previous
//
#include <hip/hip_runtime.h>

typedef __attribute__((ext_vector_type(8))) short short8;
typedef __attribute__((ext_vector_type(4))) float f32x4;
typedef __attribute__((ext_vector_type(4))) unsigned int u32x4;

#define D_DIM 1024
#define BS 64
#define TSTEPS 512

// ---------------------------------------------------------------------------
// R8: persistent recurrence, RMW-free rendezvous.
//   R7 post-mortem: ~2.5 us/step of rendezvous remained; suspect = LLC line
//   ping-pong between 16 atomic RMWs/group/step and 64 poller lanes probing
//   the same lines every ~64 cy. Changes:
//   - Per-WAVE step-stamps (one 128B line per producer wave, 64/group): after
//     its own 16B tile store drains, each wave plain-stores (relaxed agent,
//     single-writer, monotonic) the step number. NO atomic RMW anywhere.
//   - Poller (wave 0) reads all 64 slots lane-parallel + __all(f >= tgt):
//     one ~600cy memory round instead of a serialized RMW chain.
//   - Deletes both per-step intra-WG s_barriers that gated the old flag add.
//   - Staging/MFMA/layout identical to R7 -> bit-identical numerics.
// ---------------------------------------------------------------------------

// fused state planes: [plane(2)][bg(4)][kc(32)][lane(64)][hi8|lo8] bf16
// byte offset = plane*262144 + bg*65536 + kc*2048 + lane*32 + half*16
__device__ __align__(16) unsigned int g_s[2][65536];   // 512 KB total
// per-wave step-stamps: [bg(4)][ft(64)], one 128B line each (stride 32 u32)
__device__ unsigned g_flag[256 * 32];

__device__ __forceinline__ unsigned short f2bf(float f){
    union { float f; unsigned u; } v; v.f = f;
    unsigned r = v.u + 0x7FFFu + ((v.u >> 16) & 1u);   // RNE
    return (unsigned short)(r >> 16);
}
__device__ __forceinline__ float bf2f(unsigned short h){
    union { unsigned u; float f; } v; v.u = ((unsigned)h) << 16;
    return v.f;
}
__device__ __forceinline__ void split1(float f, unsigned short& h, unsigned short& l){
    h = f2bf(f);
    l = f2bf(f - bf2f(h));
}
__device__ __forceinline__ void split8(const float* __restrict__ p, short8& h8, short8& l8){
    float4 f0 = *(const float4*)p;
    float4 f1 = *(const float4*)(p + 4);
    float v[8] = {f0.x, f0.y, f0.z, f0.w, f1.x, f1.y, f1.z, f1.w};
#pragma unroll
    for (int i = 0; i < 8; ++i){
        unsigned short h, l; split1(v[i], h, l);
        h8[i] = (short)h; l8[i] = (short)l;
    }
}

// async 16B global->LDS, LLC-coherent (aux=17: sc0|sc1 -> bypass L1+L2)
__device__ __forceinline__ void gl_lds16_llc(const void* g, void* l){
    __builtin_amdgcn_global_load_lds(
        (const __attribute__((address_space(1))) void*)(unsigned long long)(uintptr_t)g,
        (__attribute__((address_space(3))) void*)(unsigned int)(unsigned long long)(uintptr_t)l,
        16, 0, 17);
}

// 16B store straight to the LLC (sc0 sc1 = agent-relaxed store semantics)
__device__ __forceinline__ void store16_llc(void* g, u32x4 v){
    asm volatile("global_store_dwordx4 %0, %1, off sc0 sc1"
                 :: "v"((unsigned long long)(uintptr_t)g), "v"(v) : "memory");
}

// ---------------- ext[r][o] = sum_j x[r][j]*Win[o][j], fp32, r = b*512+t.
// Unchanged numerics; also resets the 256 stamp lines each replay.
__global__ __launch_bounds__(256) void ext_gemm(
    const float* __restrict__ x, const float* __restrict__ Win,
    float* __restrict__ ext)
{
    if (blockIdx.x == 0 && blockIdx.y == 0)
        g_flag[threadIdx.x * 32] = 0;                // reset before recurrence

    __shared__ unsigned short Ah[64 * 40];
    __shared__ unsigned short Al[64 * 40];
    const int tid = threadIdx.x;
    const int w = tid >> 6, L = tid & 63, lh = L & 15, q = L >> 4;
    const int m0 = blockIdx.y * 64;
    const int n0 = blockIdx.x * 64 + w * 16;
    const int r_st = tid >> 2, k8 = (tid & 3) * 8;

    f32x4 acc0 = {0,0,0,0}, acc1 = {0,0,0,0}, acc2 = {0,0,0,0}, acc3 = {0,0,0,0};

    for (int kc = 0; kc < 32; ++kc){
        short8 ash, asl;
        split8(x + (size_t)(m0 + r_st) * D_DIM + kc * 32 + k8, ash, asl);
        short8 bh, bl;
        split8(Win + (size_t)(n0 + lh) * D_DIM + kc * 32 + q * 8, bh, bl);
        *(short8*)&Ah[r_st * 40 + k8] = ash;
        *(short8*)&Al[r_st * 40 + k8] = asl;
        __syncthreads();
#pragma unroll
        for (int ms = 0; ms < 4; ++ms){
            short8 ah = *(const short8*)&Ah[(ms * 16 + lh) * 40 + q * 8];
            short8 al = *(const short8*)&Al[(ms * 16 + lh) * 40 + q * 8];
            f32x4* acc = (ms == 0) ? &acc0 : (ms == 1) ? &acc1 : (ms == 2) ? &acc2 : &acc3;
            *acc = __builtin_amdgcn_mfma_f32_16x16x32_bf16(ah, bh, *acc, 0, 0, 0);
            *acc = __builtin_amdgcn_mfma_f32_16x16x32_bf16(ah, bl, *acc, 0, 0, 0);
            *acc = __builtin_amdgcn_mfma_f32_16x16x32_bf16(al, bh, *acc, 0, 0, 0);
        }
        __syncthreads();
    }

    const int col = n0 + lh;
#pragma unroll
    for (int ms = 0; ms < 4; ++ms){
        f32x4 a = (ms == 0) ? acc0 : (ms == 1) ? acc1 : (ms == 2) ? acc2 : acc3;
#pragma unroll
        for (int r = 0; r < 4; ++r){
            int row = m0 + ms * 16 + q * 4 + r;
            ext[(size_t)row * D_DIM + col] = a[r];
        }
    }
}

// ---------------- persistent recurrence: all 512 steps in one launch.
// Block j (of 64): bg = j&3 (16 batches), fblk = j>>2 (of 16); wave w
// handles ft = fblk*4 + w (16 features). 256 threads, 4 waves, 68 KB LDS.
// NOTE: ext aliases out (no __restrict__ here on purpose).
__global__ __launch_bounds__(256, 1) void recurrence(
    const float* ext, const float* Wrec, float* out)
{
    // LDS state slab: [kc(32)][plane(2: hi,lo)][lane(64)][8] = 64 KB
    __shared__ __align__(16) unsigned short st[32 * 1024];
    // per-wave transpose scratch: [wave][hi 256 | lo 256] shorts = 4 KB
    __shared__ __align__(16) unsigned short tr[4][512];

    const int tid = threadIdx.x;
    const int w = tid >> 6, L = tid & 63, lh = L & 15, q = L >> 4;
    const int j = blockIdx.x;
    const int bg = j & 3, fblk = j >> 2;
    const int ft = fblk * 4 + w;
    const int b0 = bg * 16;
    const int o  = ft * 16 + lh;
    unsigned short* trh = &tr[w][0];
    unsigned short* trl = &tr[w][256];
    char* const gsb = (char*)&g_s[0][0];
    // producer tile: 1 KB contiguous within the group slab
    const size_t tbyte = (size_t)bg * 65536 + (size_t)(ft >> 1) * 2048
                       + (size_t)(ft & 1) * 1024
                       + (size_t)(L & 31) * 32 + (size_t)(L >> 5) * 16;
    // per-lane 16B source in transpose scratch (lanes 0-31: hi, 32-63: lo)
    const int troff = (L >> 5) * 256 + (L & 31) * 8;
    // this wave's private stamp slot; wave 0 polls slot L of its group
    unsigned* const my_slot  = &g_flag[(bg * 64 + ft) * 32];
    const unsigned* poll_slot = &g_flag[(bg * 64 + L) * 32];

    // ---- pack W_rec B-fragments (hi/lo) into AGPRs: 64 x short8 = 256 regs
    short8 WH[32], WL[32];
#pragma unroll
    for (int kc = 0; kc < 32; ++kc)
        split8(Wrec + (size_t)(ft * 16 + lh) * D_DIM + kc * 32 + q * 8, WH[kc], WL[kc]);

    // ---- init: v0 = e0 -> plane 0 (transpose + one 16B LLC store per lane)
    {
        float f[4];
#pragma unroll
        for (int r = 0; r < 4; ++r)
            f[r] = ext[(size_t)(b0 + q * 4 + r) * (TSTEPS * D_DIM) + o];
#pragma unroll
        for (int r = 0; r < 4; ++r){
            unsigned short h, l; split1(f[r], h, l);
            int s = (q * 4 + r) * 8 + ((lh >> 3) << 7) + (lh & 7);
            trh[s] = h; trl[s] = l;
        }
        asm volatile("s_waitcnt lgkmcnt(0)" ::: "memory");
        __builtin_amdgcn_sched_barrier(0);
        u32x4 val = *(const u32x4*)&tr[w][troff];
        store16_llc(gsb + tbyte, val);
    }

    float ev[4];                             // prefetch e_1
#pragma unroll
    for (int r = 0; r < 4; ++r)
        ev[r] = ext[(size_t)(b0 + q * 4 + r) * (TSTEPS * D_DIM) + D_DIM + o];

    asm volatile("s_waitcnt vmcnt(4)" ::: "memory");   // own tile store drained
    if (L == 0)                                        // per-wave stamp, no RMW
        __hip_atomic_store(my_slot, 1u,
                           __ATOMIC_RELAXED, __HIP_MEMORY_SCOPE_AGENT);

#pragma unroll 1
    for (int k = 0; k < TSTEPS; ++k){
        const int p = k & 1;

        // ---- wait for state_k: wave 0 reads all 64 stamps lane-parallel
        if (w == 0){
            const unsigned tgt = (unsigned)(k + 1);
            for (;;){
                unsigned f = __hip_atomic_load(poll_slot, __ATOMIC_RELAXED,
                                               __HIP_MEMORY_SCOPE_AGENT);
                if (__all(f >= tgt)) break;
                __builtin_amdgcn_s_sleep(2);
            }
        }
        __builtin_amdgcn_s_barrier();                  // release waves 1..3
        asm volatile("" ::: "memory");                 // staging stays below

        // ---- cooperative stage (LLC-coherent, no fence needed):
        // wave w: kc {4w..4w+3} (half A) then {16+4w..19+4w} (half B).
        const char* gb = gsb + (size_t)p * 262144 + (size_t)bg * 65536;
        {
            const int ka = 4 * w, kb = 16 + 4 * w;
#pragma unroll
            for (int i = 0; i < 4; ++i){
                gl_lds16_llc(gb + (size_t)(ka + i) * 2048 + L * 32,
                             &st[(ka + i) * 1024 + L * 8]);
                gl_lds16_llc(gb + (size_t)(ka + i) * 2048 + L * 32 + 16,
                             &st[(ka + i) * 1024 + 512 + L * 8]);
            }
#pragma unroll
            for (int i = 0; i < 4; ++i){
                gl_lds16_llc(gb + (size_t)(kb + i) * 2048 + L * 32,
                             &st[(kb + i) * 1024 + L * 8]);
                gl_lds16_llc(gb + (size_t)(kb + i) * 2048 + L * 32 + 16,
                             &st[(kb + i) * 1024 + 512 + L * 8]);
            }
        }
        // half A ready: own 8 oldest staging loads done (stale ev/stamp drain)
        asm volatile("s_waitcnt vmcnt(8)" ::: "memory");
        __builtin_amdgcn_sched_barrier(0);
        __builtin_amdgcn_s_barrier();

        f32x4 aHH = {0,0,0,0}, aHL = {0,0,0,0}, aLH = {0,0,0,0};
#pragma unroll
        for (int kc = 0; kc < 16; ++kc){
            short8 ah = *(const short8*)&st[kc * 1024 + L * 8];
            short8 al = *(const short8*)&st[kc * 1024 + 512 + L * 8];
            aHH = __builtin_amdgcn_mfma_f32_16x16x32_bf16(ah, WH[kc], aHH, 0, 0, 0);
            aHL = __builtin_amdgcn_mfma_f32_16x16x32_bf16(ah, WL[kc], aHL, 0, 0, 0);
            aLH = __builtin_amdgcn_mfma_f32_16x16x32_bf16(al, WH[kc], aLH, 0, 0, 0);
        }

        // half B ready
        asm volatile("s_waitcnt vmcnt(0)" ::: "memory");
        __builtin_amdgcn_sched_barrier(0);
        __builtin_amdgcn_s_barrier();

#pragma unroll
        for (int kc = 16; kc < 32; ++kc){
            short8 ah = *(const short8*)&st[kc * 1024 + L * 8];
            short8 al = *(const short8*)&st[kc * 1024 + 512 + L * 8];
            aHH = __builtin_amdgcn_mfma_f32_16x16x32_bf16(ah, WH[kc], aHH, 0, 0, 0);
            aHL = __builtin_amdgcn_mfma_f32_16x16x32_bf16(ah, WL[kc], aHL, 0, 0, 0);
            aLH = __builtin_amdgcn_mfma_f32_16x16x32_bf16(al, WH[kc], aLH, 0, 0, 0);
        }

        if (k == TSTEPS - 1){
            // final state -> out[:,0,:] directly, full fp32 (no bf16 trip)
#pragma unroll
            for (int r = 0; r < 4; ++r){
                int b = b0 + q * 4 + r;
                out[(size_t)b * (TSTEPS * D_DIM) + o] =
                    fmaxf(aHH[r] + aHL[r] + aLH[r], 0.f);
            }
        } else {
            const int wp = p ^ 1;
            // transpose 16x16 tile into per-wave scratch, one 16B store/lane
#pragma unroll
            for (int r = 0; r < 4; ++r){
                float f = fmaxf(aHH[r] + aHL[r] + aLH[r], 0.f) + ev[r];
                unsigned short h, l; split1(f, h, l);
                int s = (q * 4 + r) * 8 + ((lh >> 3) << 7) + (lh & 7);
                trh[s] = h; trl[s] = l;
            }
            asm volatile("s_waitcnt lgkmcnt(0)" ::: "memory");
            __builtin_amdgcn_sched_barrier(0);
            {
                u32x4 val = *(const u32x4*)&tr[w][troff];
                store16_llc(gsb + (size_t)wp * 262144 + tbyte, val);
            }
            asm volatile("" ::: "memory");  // store strictly before prefetch
            if (k + 2 < TSTEPS){
                // prefetch e_{k+2}; latency hides under the next barrier wait
#pragma unroll
                for (int r = 0; r < 4; ++r)
                    ev[r] = ext[(size_t)(b0 + q * 4 + r) * (TSTEPS * D_DIM)
                                + (size_t)(k + 2) * D_DIM + o];
                asm volatile("s_waitcnt vmcnt(4)" ::: "memory");  // store drained
            } else {
                asm volatile("s_waitcnt vmcnt(0)" ::: "memory");
            }
            if (L == 0)                      // per-wave stamp, no RMW, no barrier
                __hip_atomic_store(my_slot, (unsigned)(k + 2),
                                   __ATOMIC_RELAXED, __HIP_MEMORY_SCOPE_AGENT);
        }
    }
}

// ---------------- out[:,1:,:] = 0 (out[:,0,:] holds the final state)
__global__ __launch_bounds__(256) void zero_rest(float* __restrict__ out)
{
    size_t i4 = (size_t)blockIdx.x * 256 + threadIdx.x;  // float4 index
    size_t f = i4 * 4;
    int t = (int)((f >> 10) & 511);
    if (t == 0) return;                                   // out[:,0,:] kept
    *(float4*)(out + f) = make_float4(0.f, 0.f, 0.f, 0.f);
}

extern "C" void kernel_launch(void* const* d_in, const int* in_sizes, int n_in,
                              void* d_out, int out_size, void* d_ws, size_t ws_size,
                              hipStream_t stream) {
    const float* x     = (const float*)d_in[0];   // [64][512][1024]
    const float* W_in  = (const float*)d_in[1];   // [1024][1024]
    const float* W_rec = (const float*)d_in[2];   // [1024][1024]
    float* out = (float*)d_out;

    // ext (fp32, [b][t][o]) lives in d_out — dead space until the end.
    float* ext = out;

    // 1) input projection (+ resets stamp lines for this replay)
    ext_gemm<<<dim3(16, 512), 256, 0, stream>>>(x, W_in, ext);

    // 2) all 512 recurrence steps in ONE persistent kernel (64 WGs x 256 thr)
    recurrence<<<64, 256, 0, stream>>>(ext, W_rec, out);

    // 3) zero everything except out[:,0,:]
    zero_rest<<<32768, 256, 0, stream>>>(out);
}